// Round 6
// baseline (202.156 us; speedup 1.0000x reference)
//
#include <hip/hip_runtime.h>
#include <hip/hip_bf16.h>
#include <stdint.h>

typedef __attribute__((ext_vector_type(8))) short short8;
typedef __attribute__((ext_vector_type(4))) short short4v;
typedef __attribute__((ext_vector_type(4))) float floatx4;
typedef __attribute__((ext_vector_type(16))) float floatx16;

#define M_TOT 8192
#define N_TOT 3072
#define K_TOT 1024
#define BM 128
#define BN 128
#define BK 64

__device__ inline unsigned short f2bf(float f) {
    union { float f; unsigned int ui; } v; v.f = f;
    unsigned int x = v.ui;
    unsigned int r = (x + 0x7fffu + ((x >> 16) & 1u)) >> 16; // RNE
    return (unsigned short)r;
}

__device__ inline void gl2lds16(const void* g, void* l) {
    __builtin_amdgcn_global_load_lds(
        (__attribute__((address_space(1))) void*)g,
        (__attribute__((address_space(3))) void*)l,
        16, 0, 0);
}

// ---------------------------------------------------------------------------
// Fused prep kernel (R6): rotate_w (waves 0-7, 512 thr) + cvt (waves 8-11).
// R5 ran rotate with 4 waves = 1 wave/SIMD; its inner loop (LDS b128 + 4 b32
// + FMAs) was LDS-latency-bound with nothing on the SIMD to hide it (the cvt
// wave streams HBM). R6: 8 rotate waves (2/SIMD) with halved per-thread work
// -> cross-wave LDS latency hiding; cvt keeps 4 waves (HBM-bound, ~8 us).
// Barrier matching: every wave executes exactly one __syncthreads.
// grid (48, 8) x 768 threads; LDS 97 KB -> 1 block/CU.
// ---------------------------------------------------------------------------
__global__ __launch_bounds__(768) void prep_kernel(
    const float* __restrict__ W,    // [3072,1024] fp32
    const float* __restrict__ qR,   // [8,128,128] fp32
    const float* __restrict__ kR,
    const float* __restrict__ vR,
    unsigned short* __restrict__ Fout,   // [3072,1024] bf16
    const float* __restrict__ xin,       // [8192,1024] fp32
    unsigned short* __restrict__ xb,     // [8192,1024] bf16
    int n8)                              // 1048576 groups of 8
{
    __shared__ float Rs[128 * 128]; // 64 KB
    __shared__ float Ws[64 * 132];  // 33 KB (stride-132 padded)

    const int tid = threadIdx.x;    // 0..767
    const int o0 = blockIdx.x * 64;
    const int r = blockIdx.y;

    if (tid < 512) {
        // ------------- rotate waves (0-7): stage -> barrier -> compute -----
        const float* R = (o0 < 1024) ? qR : (o0 < 2048) ? kR : vR;
        R += (size_t)r * 128 * 128;

        // stage Rs: 16384 floats, 512 threads x 8 float4
#pragma unroll
        for (int i = 0; i < 8; ++i) {
            int idx = (i * 512 + tid) * 4;
            *(float4*)(Rs + idx) = *(const float4*)(R + idx);
        }
        // stage Ws: 64 rows x 128 cols, 512 threads x 4 float4
#pragma unroll
        for (int i = 0; i < 4; ++i) {
            int idx = (i * 512 + tid) * 4;
            int row = idx >> 7;
            int col = idx & 127;
            *(float4*)(Ws + row * 132 + col) =
                *(const float4*)(W + (size_t)(o0 + row) * K_TOT + r * 128 + col);
        }
        __syncthreads();

        const int jg = (tid & 31) * 4;  // j base (0,4,...,124)
        const int ob = tid >> 5;        // 0..15

        float acc[4][4];
#pragma unroll
        for (int a = 0; a < 4; ++a)
#pragma unroll
            for (int b = 0; b < 4; ++b) acc[a][b] = 0.f;

        for (int i = 0; i < 128; ++i) {
            float4 r0 = *(const float4*)(Rs + i * 128 + jg);
            float rv[4] = {r0.x, r0.y, r0.z, r0.w};
#pragma unroll
            for (int oo = 0; oo < 4; ++oo) {
                float wv = Ws[(ob + oo * 16) * 132 + i];  // wave-uniform pair
#pragma unroll
                for (int t = 0; t < 4; ++t) acc[oo][t] += wv * rv[t];
            }
        }

#pragma unroll
        for (int oo = 0; oo < 4; ++oo) {
            int o = o0 + ob + oo * 16;
            short4v s;
#pragma unroll
            for (int t = 0; t < 4; ++t) s[t] = (short)f2bf(acc[oo][t]);
            *(short4v*)(Fout + (size_t)o * K_TOT + r * 128 + jg) = s;
        }
    } else {
        // ------------- cvt waves (8-11): barrier (immediate) -> stream -----
        __syncthreads();
        const int gbid = r * 48 + blockIdx.x;          // 0..383
        int g = gbid * 256 + (tid - 512);              // 256 cvt threads/block
        for (; g < n8; g += 384 * 256) {
            const float4* p = (const float4*)xin + (size_t)g * 2;
            float4 a = p[0], b = p[1];
            short8 s;
            s[0] = (short)f2bf(a.x); s[1] = (short)f2bf(a.y);
            s[2] = (short)f2bf(a.z); s[3] = (short)f2bf(a.w);
            s[4] = (short)f2bf(b.x); s[5] = (short)f2bf(b.y);
            s[6] = (short)f2bf(b.z); s[7] = (short)f2bf(b.w);
            *(short8*)(xb + (size_t)g * 8) = s;
        }
    }
}

// ---------------------------------------------------------------------------
// GEMM: proven R0 kernel, UNCHANGED (70 us, MfmaUtil ~30%).
// out[m,n] = sum_k X[m,k]*F[n,k] + bias[n]   (bias/out fp32)
// 128x128 tile, BK=64, 4 waves (2x2); per wave 2x2 tiles of 32x32x16 MFMA.
// Latin-square LDS swizzle: LDS[row][cg] = G[row][cg ^ f(row)],
//   f(row) = (row&7) ^ 2*((row>>3)&3)
// C/D (32x32): col=lane&31, row=(reg&3)+8*(reg>>2)+4*(lane>>5) [m74/m101].
// Epilogue bounced through LDS for full-line float4 global stores (no RFO).
// ---------------------------------------------------------------------------
__global__ void gemm_bt_kernel(
    const unsigned short* __restrict__ X,  // [8192,1024] bf16 (ws)
    const unsigned short* __restrict__ F,  // [3072,1024] bf16 (ws)
    const float* __restrict__ bias,        // [3072] fp32
    float* __restrict__ out)               // [8192,3072] fp32
{
    __shared__ __align__(16) unsigned char smem[2 * BM * BK * sizeof(unsigned short)];
    unsigned short* As = (unsigned short*)smem;            // 16 KB
    unsigned short* Bs = As + BM * BK;                     // 16 KB
    float* Cs = (float*)smem;                              // 32 KB = 64x128 fp32

    const int tid = threadIdx.x;
    const int wave = tid >> 6;
    const int lane = tid & 63;
    const int m0 = blockIdx.x * BM;
    const int n0 = blockIdx.y * BN;

    const int wm = wave >> 1; // 0..1
    const int wn = wave & 1;  // 0..1
    const int l31 = lane & 31;
    const int khalf = lane >> 5;

    // staging: per instr p, wave covers 8 rows (lane>>3) x 8 colgroups (lane&7)
    const int srow_lane = lane >> 3;              // 0..7  == row & 7

    floatx16 acc[2][2];
#pragma unroll
    for (int a = 0; a < 2; ++a)
#pragma unroll
        for (int b = 0; b < 2; ++b)
#pragma unroll
            for (int t = 0; t < 16; ++t) acc[a][b][t] = 0.f;

    // fragment-read swizzle term: f(row), row&7 = l31&7, (row>>3)&3 = (l31>>3)&3
    const int fr_read = (l31 & 7) ^ (((l31 >> 3) & 3) << 1);

    for (int k0 = 0; k0 < K_TOT; k0 += BK) {
#pragma unroll
        for (int p = 0; p < 4; ++p) {
            const int rr = (wave * 4 + p) * 8 + srow_lane;
            // f(rr) = srow_lane ^ 2*((wave*4+p)&3)
            const int scg = (lane & 7) ^ srow_lane ^ ((((wave * 4 + p) & 3)) << 1);
            const int scol = scg * 8;
            gl2lds16(X + (size_t)(m0 + rr) * K_TOT + k0 + scol,
                     As + (wave * 4 + p) * 512 + lane * 8);
            gl2lds16(F + (size_t)(n0 + rr) * K_TOT + k0 + scol,
                     Bs + (wave * 4 + p) * 512 + lane * 8);
        }
        __syncthreads();

#pragma unroll
        for (int ks = 0; ks < 4; ++ks) {
            const int fcg = ((ks * 2 + khalf) ^ fr_read) * 8;
            short8 a[2], b[2];
#pragma unroll
            for (int mi = 0; mi < 2; ++mi)
                a[mi] = *(const short8*)(As + (wm * 64 + mi * 32 + l31) * BK + fcg);
#pragma unroll
            for (int ni = 0; ni < 2; ++ni)
                b[ni] = *(const short8*)(Bs + (wn * 64 + ni * 32 + l31) * BK + fcg);
#pragma unroll
            for (int mi = 0; mi < 2; ++mi)
#pragma unroll
                for (int ni = 0; ni < 2; ++ni)
                    acc[mi][ni] = __builtin_amdgcn_mfma_f32_32x32x16_bf16(
                        a[mi], b[ni], acc[mi][ni], 0, 0, 0);
        }
        __syncthreads();
    }

    // ---- Epilogue via LDS: two 64-row halves, full-line float4 stores ----
    float bv[2];
#pragma unroll
    for (int ni = 0; ni < 2; ++ni)
        bv[ni] = bias[n0 + wn * 64 + ni * 32 + l31];

#pragma unroll
    for (int h = 0; h < 2; ++h) {
        if (wm == h) {
#pragma unroll
            for (int mi = 0; mi < 2; ++mi)
#pragma unroll
                for (int ni = 0; ni < 2; ++ni) {
                    const int col = wn * 64 + ni * 32 + l31;
#pragma unroll
                    for (int reg = 0; reg < 16; ++reg) {
                        const int row = mi * 32 + (reg & 3) + 8 * (reg >> 2) +
                                        4 * khalf;
                        Cs[row * 128 + col] = acc[mi][ni][reg] + bv[ni];
                    }
                }
        }
        __syncthreads();
        // 256 threads store 64 rows x 128 cols fp32: 8 rounds of float4
#pragma unroll
        for (int t = 0; t < 8; ++t) {
            const int idx = t * 256 + tid;       // 0..2047
            const int row = idx >> 5;            // 32 float4 per row
            const int c4 = (idx & 31) * 4;
            float4 v = *(const float4*)(Cs + row * 128 + c4);
            *(float4*)(out + (size_t)(m0 + h * 64 + row) * N_TOT + n0 + c4) = v;
        }
        __syncthreads();
    }
}

extern "C" void kernel_launch(void* const* d_in, const int* in_sizes, int n_in,
                              void* d_out, int out_size, void* d_ws, size_t ws_size,
                              hipStream_t stream) {
    const float* attn = (const float*)d_in[0]; // [3072,1024] fp32
    const float* bias = (const float*)d_in[1]; // [3072] fp32
    const float* x    = (const float*)d_in[2]; // [4,2048,1024] fp32
    const float* qR   = (const float*)d_in[3]; // [8,128,128] fp32
    const float* kR   = (const float*)d_in[4];
    const float* vR   = (const float*)d_in[5];

    float* out = (float*)d_out; // [4,2048,3072] fp32

    // ws layout: xb [8192*1024] bf16 (16 MB) | filt [3072*1024] bf16 (6 MB)
    unsigned short* xb   = (unsigned short*)d_ws;
    unsigned short* filt = xb + (size_t)M_TOT * K_TOT;

    const int n8 = (M_TOT * K_TOT) / 8; // 1,048,576
    prep_kernel<<<dim3(48, 8), 768, 0, stream>>>(attn, qR, kR, vR, filt,
                                                 x, xb, n8);
    gemm_bt_kernel<<<dim3(M_TOT / BM, N_TOT / BN), 256, 0, stream>>>(
        xb, filt, bias, out);
}

// Round 7
// 199.245 us; speedup vs baseline: 1.0146x; 1.0146x over previous
//
#include <hip/hip_runtime.h>
#include <hip/hip_bf16.h>
#include <stdint.h>

typedef __attribute__((ext_vector_type(8))) short short8;
typedef __attribute__((ext_vector_type(4))) float floatx4;
typedef __attribute__((ext_vector_type(16))) float floatx16;

#define M_TOT 8192
#define N_TOT 3072
#define K_TOT 1024
#define BM 128
#define BN 128
#define BK 64

__device__ inline unsigned short f2bf(float f) {
    union { float f; unsigned int ui; } v; v.f = f;
    unsigned int x = v.ui;
    unsigned int r = (x + 0x7fffu + ((x >> 16) & 1u)) >> 16; // RNE
    return (unsigned short)r;
}

__device__ inline void gl2lds16(const void* g, void* l) {
    __builtin_amdgcn_global_load_lds(
        (__attribute__((address_space(1))) void*)g,
        (__attribute__((address_space(3))) void*)l,
        16, 0, 0);
}

// ---------------------------------------------------------------------------
// Fused prep kernel (R7): rotate_w (waves 0-3, R5-VERBATIM) + cvt (waves
// 4-11, widened 4->8 waves).
// R5 (4 rotate + 4 cvt) = 199.9 us total; R6's rotate rebalance regressed
// (202.2) -> rotate restored exactly. Only the cvt side changes: 512 cvt
// threads instead of 256, to push the 48 MB HBM stream (~10 us at 4 waves)
// toward the ~7.6 us BW floor. cvt touches no LDS; barrier matching: every
// wave executes exactly one __syncthreads.
// grid (48, 8) x 768 threads; LDS 97 KB -> 1 block/CU.
// ---------------------------------------------------------------------------
__global__ __launch_bounds__(768) void prep_kernel(
    const float* __restrict__ W,    // [3072,1024] fp32
    const float* __restrict__ qR,   // [8,128,128] fp32
    const float* __restrict__ kR,
    const float* __restrict__ vR,
    unsigned short* __restrict__ Fout,   // [3072,1024] bf16
    const float* __restrict__ xin,       // [8192,1024] fp32
    unsigned short* __restrict__ xb,     // [8192,1024] bf16
    int n8)                              // 1048576 groups of 8
{
    __shared__ float Rs[128 * 128]; // 64 KB
    __shared__ float Ws[64 * 132];  // 33 KB (stride-132 padded)

    const int tid = threadIdx.x;    // 0..767
    const int o0 = blockIdx.x * 64;
    const int r = blockIdx.y;

    if (tid < 256) {
        // -------- rotate waves (0-3): stage -> barrier -> compute ----------
        // (verbatim R5 body; 256 threads)
        const float* R = (o0 < 1024) ? qR : (o0 < 2048) ? kR : vR;
        R += (size_t)r * 128 * 128;

#pragma unroll
        for (int i = 0; i < 16; ++i) {
            int idx = (i * 256 + tid) * 4;
            *(float4*)(Rs + idx) = *(const float4*)(R + idx);
        }
#pragma unroll
        for (int i = 0; i < 8; ++i) {
            int idx = (i * 256 + tid) * 4;
            int row = idx >> 7;
            int col = idx & 127;
            *(float4*)(Ws + row * 132 + col) =
                *(const float4*)(W + (size_t)(o0 + row) * K_TOT + r * 128 + col);
        }
        __syncthreads();

        const int jg = (tid & 15) * 8;  // j base (0,8,...,120)
        const int ob = tid >> 4;        // 0..15

        float acc[4][8];
#pragma unroll
        for (int a = 0; a < 4; ++a)
#pragma unroll
            for (int b = 0; b < 8; ++b) acc[a][b] = 0.f;

        for (int i = 0; i < 128; ++i) {
            float4 r0 = *(const float4*)(Rs + i * 128 + jg);
            float4 r1 = *(const float4*)(Rs + i * 128 + jg + 4);
            float rv[8] = {r0.x, r0.y, r0.z, r0.w, r1.x, r1.y, r1.z, r1.w};
#pragma unroll
            for (int oo = 0; oo < 4; ++oo) {
                float wv = Ws[(ob + oo * 16) * 132 + i];
#pragma unroll
                for (int t = 0; t < 8; ++t) acc[oo][t] += wv * rv[t];
            }
        }

#pragma unroll
        for (int oo = 0; oo < 4; ++oo) {
            int o = o0 + ob + oo * 16;
            short8 s;
#pragma unroll
            for (int t = 0; t < 8; ++t) s[t] = (short)f2bf(acc[oo][t]);
            *(short8*)(Fout + (size_t)o * K_TOT + r * 128 + jg) = s;
        }
    } else {
        // -------- cvt waves (4-11): barrier (immediate) -> stream ----------
        __syncthreads();
        const int gbid = r * 48 + blockIdx.x;          // 0..383
        int g = gbid * 512 + (tid - 256);              // 512 cvt threads/block
        for (; g < n8; g += 384 * 512) {
            const float4* p = (const float4*)xin + (size_t)g * 2;
            float4 a = p[0], b = p[1];
            short8 s;
            s[0] = (short)f2bf(a.x); s[1] = (short)f2bf(a.y);
            s[2] = (short)f2bf(a.z); s[3] = (short)f2bf(a.w);
            s[4] = (short)f2bf(b.x); s[5] = (short)f2bf(b.y);
            s[6] = (short)f2bf(b.z); s[7] = (short)f2bf(b.w);
            *(short8*)(xb + (size_t)g * 8) = s;
        }
    }
}

// ---------------------------------------------------------------------------
// GEMM: proven R0 kernel, UNCHANGED (70 us, MfmaUtil ~30%).
// out[m,n] = sum_k X[m,k]*F[n,k] + bias[n]   (bias/out fp32)
// 128x128 tile, BK=64, 4 waves (2x2); per wave 2x2 tiles of 32x32x16 MFMA.
// Latin-square LDS swizzle: LDS[row][cg] = G[row][cg ^ f(row)],
//   f(row) = (row&7) ^ 2*((row>>3)&3)
// Residual 6.29M conflict cycles are INHERENT to 32-lane b128 column reads
// at 128B row stride (>=4-way: bank group = 3-bit col-slot; 32 lanes / 8
// slots). Only a 16x16-frag geometry escapes, at +21% MFMA-pipe cost — not
// worth the churn (4/4 restructure attempts failed at this node).
// C/D (32x32): col=lane&31, row=(reg&3)+8*(reg>>2)+4*(lane>>5) [m74/m101].
// Epilogue bounced through LDS for full-line float4 global stores (no RFO).
// ---------------------------------------------------------------------------
__global__ void gemm_bt_kernel(
    const unsigned short* __restrict__ X,  // [8192,1024] bf16 (ws)
    const unsigned short* __restrict__ F,  // [3072,1024] bf16 (ws)
    const float* __restrict__ bias,        // [3072] fp32
    float* __restrict__ out)               // [8192,3072] fp32
{
    __shared__ __align__(16) unsigned char smem[2 * BM * BK * sizeof(unsigned short)];
    unsigned short* As = (unsigned short*)smem;            // 16 KB
    unsigned short* Bs = As + BM * BK;                     // 16 KB
    float* Cs = (float*)smem;                              // 32 KB = 64x128 fp32

    const int tid = threadIdx.x;
    const int wave = tid >> 6;
    const int lane = tid & 63;
    const int m0 = blockIdx.x * BM;
    const int n0 = blockIdx.y * BN;

    const int wm = wave >> 1; // 0..1
    const int wn = wave & 1;  // 0..1
    const int l31 = lane & 31;
    const int khalf = lane >> 5;

    // staging: per instr p, wave covers 8 rows (lane>>3) x 8 colgroups (lane&7)
    const int srow_lane = lane >> 3;              // 0..7  == row & 7

    floatx16 acc[2][2];
#pragma unroll
    for (int a = 0; a < 2; ++a)
#pragma unroll
        for (int b = 0; b < 2; ++b)
#pragma unroll
            for (int t = 0; t < 16; ++t) acc[a][b][t] = 0.f;

    // fragment-read swizzle term: f(row), row&7 = l31&7, (row>>3)&3 = (l31>>3)&3
    const int fr_read = (l31 & 7) ^ (((l31 >> 3) & 3) << 1);

    for (int k0 = 0; k0 < K_TOT; k0 += BK) {
#pragma unroll
        for (int p = 0; p < 4; ++p) {
            const int rr = (wave * 4 + p) * 8 + srow_lane;
            // f(rr) = srow_lane ^ 2*((wave*4+p)&3)
            const int scg = (lane & 7) ^ srow_lane ^ ((((wave * 4 + p) & 3)) << 1);
            const int scol = scg * 8;
            gl2lds16(X + (size_t)(m0 + rr) * K_TOT + k0 + scol,
                     As + (wave * 4 + p) * 512 + lane * 8);
            gl2lds16(F + (size_t)(n0 + rr) * K_TOT + k0 + scol,
                     Bs + (wave * 4 + p) * 512 + lane * 8);
        }
        __syncthreads();

#pragma unroll
        for (int ks = 0; ks < 4; ++ks) {
            const int fcg = ((ks * 2 + khalf) ^ fr_read) * 8;
            short8 a[2], b[2];
#pragma unroll
            for (int mi = 0; mi < 2; ++mi)
                a[mi] = *(const short8*)(As + (wm * 64 + mi * 32 + l31) * BK + fcg);
#pragma unroll
            for (int ni = 0; ni < 2; ++ni)
                b[ni] = *(const short8*)(Bs + (wn * 64 + ni * 32 + l31) * BK + fcg);
#pragma unroll
            for (int mi = 0; mi < 2; ++mi)
#pragma unroll
                for (int ni = 0; ni < 2; ++ni)
                    acc[mi][ni] = __builtin_amdgcn_mfma_f32_32x32x16_bf16(
                        a[mi], b[ni], acc[mi][ni], 0, 0, 0);
        }
        __syncthreads();
    }

    // ---- Epilogue via LDS: two 64-row halves, full-line float4 stores ----
    float bv[2];
#pragma unroll
    for (int ni = 0; ni < 2; ++ni)
        bv[ni] = bias[n0 + wn * 64 + ni * 32 + l31];

#pragma unroll
    for (int h = 0; h < 2; ++h) {
        if (wm == h) {
#pragma unroll
            for (int mi = 0; mi < 2; ++mi)
#pragma unroll
                for (int ni = 0; ni < 2; ++ni) {
                    const int col = wn * 64 + ni * 32 + l31;
#pragma unroll
                    for (int reg = 0; reg < 16; ++reg) {
                        const int row = mi * 32 + (reg & 3) + 8 * (reg >> 2) +
                                        4 * khalf;
                        Cs[row * 128 + col] = acc[mi][ni][reg] + bv[ni];
                    }
                }
        }
        __syncthreads();
        // 256 threads store 64 rows x 128 cols fp32: 8 rounds of float4
#pragma unroll
        for (int t = 0; t < 8; ++t) {
            const int idx = t * 256 + tid;       // 0..2047
            const int row = idx >> 5;            // 32 float4 per row
            const int c4 = (idx & 31) * 4;
            float4 v = *(const float4*)(Cs + row * 128 + c4);
            *(float4*)(out + (size_t)(m0 + h * 64 + row) * N_TOT + n0 + c4) = v;
        }
        __syncthreads();
    }
}

extern "C" void kernel_launch(void* const* d_in, const int* in_sizes, int n_in,
                              void* d_out, int out_size, void* d_ws, size_t ws_size,
                              hipStream_t stream) {
    const float* attn = (const float*)d_in[0]; // [3072,1024] fp32
    const float* bias = (const float*)d_in[1]; // [3072] fp32
    const float* x    = (const float*)d_in[2]; // [4,2048,1024] fp32
    const float* qR   = (const float*)d_in[3]; // [8,128,128] fp32
    const float* kR   = (const float*)d_in[4];
    const float* vR   = (const float*)d_in[5];

    float* out = (float*)d_out; // [4,2048,3072] fp32

    // ws layout: xb [8192*1024] bf16 (16 MB) | filt [3072*1024] bf16 (6 MB)
    unsigned short* xb   = (unsigned short*)d_ws;
    unsigned short* filt = xb + (size_t)M_TOT * K_TOT;

    const int n8 = (M_TOT * K_TOT) / 8; // 1,048,576
    prep_kernel<<<dim3(48, 8), 768, 0, stream>>>(attn, qR, kR, vR, filt,
                                                 x, xb, n8);
    gemm_bt_kernel<<<dim3(M_TOT / BM, N_TOT / BN), 256, 0, stream>>>(
        xb, filt, bias, out);
}